// Round 5
// baseline (372.006 us; speedup 1.0000x reference)
//
#include <hip/hip_runtime.h>
#include <cstdint>
#include <cstddef>

// ---------------------------------------------------------------------------
// y[b,o] = sum_{i,j<257} x1[b,i] x1[b,j] W[o, i*257+j] + bias[o],  x1=[1,x]
//   main : slices ii in [0,258) (257 real + pseudo 257=j-col 256), j in [0,256)
//   corner (256,256) + bias -> init_out kernel (exact fp32)
// GEMM M=2048 N=256, 258 slices x 8 j-chunks of 32.
// Round 5: round-4 structure + the pseudo-slice scalar clamp fix
// (scalar for slice ii is x1[min(ii,256)]; round 4 read the zero pad at 257).
// jc-pair outer / slice inner. Zero LDS, zero barriers. Per-wave live set
// ~115 VGPR: acc[2][4]=32, W dbuf=32, x1 jc-pair base=16, slice scalars 9.
// BM=32, 4-wave blocks, grid 2048 = 4 blocks/CU x 2 rounds; co-resident
// blocks share split -> W stream L1/L2-reused x4. Split->XCD pinned (s%8).
// ---------------------------------------------------------------------------

typedef _Float16 half8 __attribute__((ext_vector_type(8)));
typedef float    f32x4 __attribute__((ext_vector_type(4)));

#define LD8(p) (*(const half8*)(p))

// ---- stage 1: W [256][66049] f32 -> Wp [o][ii(258)][j(256)] f16 -------------
__global__ void conv_w_k(const float* __restrict__ W, _Float16* __restrict__ Wp) {
  int t   = blockIdx.x * 256 + threadIdx.x;   // total 256*258*32 = 2,113,536
  int j8  = t & 31;
  int rem = t >> 5;
  int ii  = rem % 258;
  int o   = rem / 258;
  float v[8];
  if (ii < 257) {
    const float* src = W + (size_t)o * 66049 + ii * 257 + j8 * 8;
#pragma unroll
    for (int u = 0; u < 8; ++u) v[u] = src[u];
  } else {
    const float* src = W + (size_t)o * 66049 + 256;
#pragma unroll
    for (int u = 0; u < 8; ++u) v[u] = src[(size_t)(j8 * 8 + u) * 257];
  }
  half8 h;
#pragma unroll
  for (int u = 0; u < 8; ++u) h[u] = (_Float16)v[u];
  *(half8*)(Wp + ((size_t)o * 258 + ii) * 256 + j8 * 8) = h;
}

// ---- stage 1b: x [2048][256] f32 -> X1g [2048][264] f16 (x1 padded) ---------
__global__ void conv_x1_k(const float* __restrict__ x, _Float16* __restrict__ X1g) {
  int t  = blockIdx.x * 256 + threadIdx.x;    // total 2048*33 = 67584
  int j8 = t % 33;
  int b  = t / 33;
  half8 h;
#pragma unroll
  for (int u = 0; u < 8; ++u) {
    int jj = j8 * 8 + u;
    float v = (jj == 0) ? 1.0f : (jj <= 256 ? x[(size_t)b * 256 + (jj - 1)] : 0.0f);
    h[u] = (_Float16)v;
  }
  *(half8*)(X1g + (size_t)b * 264 + j8 * 8) = h;
}

// ---- init: Y = bias + x1[256]^2 * W[o,66048]  (exact fp32 terms) ------------
__global__ void init_out_k(const float* __restrict__ x, const float* __restrict__ W,
                           const float* __restrict__ bias, float* __restrict__ Y) {
  int o = threadIdx.x;
  int b = blockIdx.x;
  float xl = x[(size_t)b * 256 + 255];
  float w  = W[(size_t)o * 66049 + 66048];
  Y[(size_t)b * 256 + o] = bias[o] + xl * xl * w;
}

// ---- main-loop core: 4 jc-pairs x 2*NII steps, fully static slots -----------
template<int NII>
__device__ __forceinline__ void core_fn(
    const _Float16* __restrict__ wq0, const _Float16* __restrict__ wq1,
    const _Float16* __restrict__ wq2, const _Float16* __restrict__ wq3,
    const _Float16* __restrict__ x0,  const _Float16* __restrict__ x1r,
    half8 s80, half8 s81, _Float16 s90, _Float16 s91,
    f32x4 acc[2][4])
{
  half8 sA0, sA1, sA2, sA3, sB0, sB1, sB2, sB3;
  half8 bA0, bA1, bB0, bB1;

  // prologue: base for jc=0/1, W slots for steps (jc0=0,k=0) and (jc0=0,k=1)
  bA0 = LD8(x0);       bA1 = LD8(x1r);
  bB0 = LD8(x0 + 32);  bB1 = LD8(x1r + 32);
  sA0 = LD8(wq0);       sA1 = LD8(wq1);       sA2 = LD8(wq2);       sA3 = LD8(wq3);
  sB0 = LD8(wq0 + 256); sB1 = LD8(wq1 + 256); sB2 = LD8(wq2 + 256); sB3 = LD8(wq3 + 256);

  for (int jp = 0; jp < 4; ++jp) {
    const int jc0 = 2 * jp;
    const int jcn = (jp < 3) ? jc0 + 2 : 0;     // next-pair jc (clamped: jp=3 dummy)
    const _Float16* q0 = wq0 + jc0 * 32;
    const _Float16* q1 = wq1 + jc0 * 32;
    const _Float16* q2 = wq2 + jc0 * 32;
    const _Float16* q3 = wq3 + jc0 * 32;
    const _Float16* r0 = wq0 + jcn * 32;
    const _Float16* r1 = wq1 + jcn * 32;
    const _Float16* r2 = wq2 + jcn * 32;
    const _Float16* r3 = wq3 + jcn * 32;
    const _Float16* xa0 = x0  + jcn * 32;       // baseA refill (next pair, 1st half)
    const _Float16* xa1 = x1r + jcn * 32;
    const _Float16* xb0 = x0  + jcn * 32 + 32;  // baseB refill (next pair, 2nd half)
    const _Float16* xb1 = x1r + jcn * 32 + 32;

#pragma unroll
    for (int q = 0; q < 2 * NII; ++q) {
      const int k = (q < NII) ? q : q - NII;    // slice offset (compile-time)
      _Float16 e0 = (k < 8) ? s80[k] : s90;
      _Float16 e1 = (k < 8) ? s81[k] : s91;
      half8 v0 = {e0, e0, e0, e0, e0, e0, e0, e0};
      half8 v1 = {e1, e1, e1, e1, e1, e1, e1, e1};
      half8 af0 = ((q < NII) ? bA0 : bB0) * v0;   // v_pk_mul_f16
      half8 af1 = ((q < NII) ? bA1 : bB1) * v1;

      __builtin_amdgcn_s_setprio(1);
      if ((q & 1) == 0) {
        acc[0][0] = __builtin_amdgcn_mfma_f32_16x16x32_f16(af0, sA0, acc[0][0], 0, 0, 0);
        acc[0][1] = __builtin_amdgcn_mfma_f32_16x16x32_f16(af0, sA1, acc[0][1], 0, 0, 0);
        acc[0][2] = __builtin_amdgcn_mfma_f32_16x16x32_f16(af0, sA2, acc[0][2], 0, 0, 0);
        acc[0][3] = __builtin_amdgcn_mfma_f32_16x16x32_f16(af0, sA3, acc[0][3], 0, 0, 0);
        acc[1][0] = __builtin_amdgcn_mfma_f32_16x16x32_f16(af1, sA0, acc[1][0], 0, 0, 0);
        acc[1][1] = __builtin_amdgcn_mfma_f32_16x16x32_f16(af1, sA1, acc[1][1], 0, 0, 0);
        acc[1][2] = __builtin_amdgcn_mfma_f32_16x16x32_f16(af1, sA2, acc[1][2], 0, 0, 0);
        acc[1][3] = __builtin_amdgcn_mfma_f32_16x16x32_f16(af1, sA3, acc[1][3], 0, 0, 0);
      } else {
        acc[0][0] = __builtin_amdgcn_mfma_f32_16x16x32_f16(af0, sB0, acc[0][0], 0, 0, 0);
        acc[0][1] = __builtin_amdgcn_mfma_f32_16x16x32_f16(af0, sB1, acc[0][1], 0, 0, 0);
        acc[0][2] = __builtin_amdgcn_mfma_f32_16x16x32_f16(af0, sB2, acc[0][2], 0, 0, 0);
        acc[0][3] = __builtin_amdgcn_mfma_f32_16x16x32_f16(af0, sB3, acc[0][3], 0, 0, 0);
        acc[1][0] = __builtin_amdgcn_mfma_f32_16x16x32_f16(af1, sB0, acc[1][0], 0, 0, 0);
        acc[1][1] = __builtin_amdgcn_mfma_f32_16x16x32_f16(af1, sB1, acc[1][1], 0, 0, 0);
        acc[1][2] = __builtin_amdgcn_mfma_f32_16x16x32_f16(af1, sB2, acc[1][2], 0, 0, 0);
        acc[1][3] = __builtin_amdgcn_mfma_f32_16x16x32_f16(af1, sB3, acc[1][3], 0, 0, 0);
      }
      __builtin_amdgcn_s_setprio(0);

      // prefetch step q+2 into the slot just consumed (double buffer)
      const int qq = q + 2;
      if (qq < 2 * NII) {
        const int koff = ((qq < NII) ? qq : qq - NII) * 256 + ((qq < NII) ? 0 : 32);
        if ((q & 1) == 0) {
          sA0 = LD8(q0 + koff); sA1 = LD8(q1 + koff);
          sA2 = LD8(q2 + koff); sA3 = LD8(q3 + koff);
        } else {
          sB0 = LD8(q0 + koff); sB1 = LD8(q1 + koff);
          sB2 = LD8(q2 + koff); sB3 = LD8(q3 + koff);
        }
      } else {
        const int koff = (qq - 2 * NII) * 256;   // steps 0/1 of next pair
        if ((q & 1) == 0) {
          sA0 = LD8(r0 + koff); sA1 = LD8(r1 + koff);
          sA2 = LD8(r2 + koff); sA3 = LD8(r3 + koff);
        } else {
          sB0 = LD8(r0 + koff); sB1 = LD8(r1 + koff);
          sB2 = LD8(r2 + koff); sB3 = LD8(r3 + koff);
        }
      }
      if (q == NII)         { bA0 = LD8(xa0); bA1 = LD8(xa1); }
      if (q == 2 * NII - 1) { bB0 = LD8(xb0); bB1 = LD8(xb1); }
    }
  }
}

// ---- main GEMM: virtual A = x1[b,ii] * x1[b,j], B = Wp streamed to VGPR -----
__global__ __launch_bounds__(256, 4)
void gemm_k(const _Float16* __restrict__ Wp, const _Float16* __restrict__ X1g,
            float* __restrict__ Y) {
  const int bid = blockIdx.x;
  const int s   = bid & 31;             // split -> XCD s%8 (L2 pinning)
  const int mt  = bid >> 5;             // m-tile (BM=32), 0..63
  const int ii0 = s * 8 + (s < 2 ? s : 2);   // splits 0,1: NII=9; else 8

  const int tid = threadIdx.x;
  const int l   = tid & 63;
  const int w   = tid >> 6;   // wave = n-group (64 cols)
  const int ln  = l & 15;
  const int ks  = l >> 4;

  const int row0 = mt * 32 + ln;
  const int row1 = row0 + 16;
  const _Float16* x0  = X1g + (size_t)row0 * 264 + ks * 8;
  const _Float16* x1r = X1g + (size_t)row1 * 264 + ks * 8;

  // per-slice scalars: x1[row, min(ii0+k, 256)] — CLAMP: pseudo-slice 257's
  // scalar is x1[256], NOT the zero pad (round-4 bug).
  half8 s80, s81;
#pragma unroll
  for (int k = 0; k < 8; ++k) {
    int idx = ii0 + k; if (idx > 256) idx = 256;
    s80[k] = X1g[(size_t)row0 * 264 + idx];
    s81[k] = X1g[(size_t)row1 * 264 + idx];
  }
  _Float16 s90 = (_Float16)0.f, s91 = (_Float16)0.f;
  if (s < 2) {
    int idx = ii0 + 8; if (idx > 256) idx = 256;
    s90 = X1g[(size_t)row0 * 264 + idx];
    s91 = X1g[(size_t)row1 * 264 + idx];
  }

  const _Float16* wq0 = Wp + (size_t)(w * 64 +  0 + ln) * 66048 + ii0 * 256 + ks * 8;
  const _Float16* wq1 = Wp + (size_t)(w * 64 + 16 + ln) * 66048 + ii0 * 256 + ks * 8;
  const _Float16* wq2 = Wp + (size_t)(w * 64 + 32 + ln) * 66048 + ii0 * 256 + ks * 8;
  const _Float16* wq3 = Wp + (size_t)(w * 64 + 48 + ln) * 66048 + ii0 * 256 + ks * 8;

  f32x4 acc[2][4];
#pragma unroll
  for (int mf = 0; mf < 2; ++mf)
#pragma unroll
    for (int nf = 0; nf < 4; ++nf) acc[mf][nf] = (f32x4){0.f, 0.f, 0.f, 0.f};

  if (s < 2) core_fn<9>(wq0, wq1, wq2, wq3, x0, x1r, s80, s81, s90, s91, acc);
  else       core_fn<8>(wq0, wq1, wq2, wq3, x0, x1r, s80, s81, s90, s91, acc);

  // ---- epilogue: atomic accumulate (C/D: col=l&15, row=ks*4+r) ----
  float* yb = Y + (size_t)(mt * 32) * 256 + w * 64;
  const int r0 = ks * 4;
#pragma unroll
  for (int mf = 0; mf < 2; ++mf)
#pragma unroll
    for (int nf = 0; nf < 4; ++nf)
#pragma unroll
      for (int r = 0; r < 4; ++r)
        unsafeAtomicAdd(&yb[(size_t)(mf * 16 + r0 + r) * 256 + nf * 16 + ln],
                        acc[mf][nf][r]);
}

// ---- emergency fallback if ws too small (correct, slow) ---------------------
__global__ void fb_k(const float* __restrict__ x, const float* __restrict__ W,
                     const float* __restrict__ bias, float* __restrict__ Y) {
  __shared__ float x1[257];
  int b = blockIdx.x, o = threadIdx.x;
  x1[o + 1] = x[(size_t)b * 256 + o];
  if (o == 0) x1[0] = 1.0f;
  __syncthreads();
  const float* Wr = W + (size_t)o * 66049;
  float acc = bias[o];
  for (int i = 0; i < 257; ++i) {
    const float* wr = Wr + (size_t)i * 257;
    float p = 0.f;
    for (int j = 0; j < 257; ++j) p = fmaf(x1[j], wr[j], p);
    acc = fmaf(x1[i], p, acc);
  }
  Y[(size_t)b * 256 + o] = acc;
}

extern "C" void kernel_launch(void* const* d_in, const int* in_sizes, int n_in,
                              void* d_out, int out_size, void* d_ws, size_t ws_size,
                              hipStream_t stream) {
  const float* x = (const float*)d_in[0];
  const float* W = (const float*)d_in[1];
  const float* b = (const float*)d_in[2];
  float* y = (float*)d_out;

  const size_t WPB = (size_t)256 * 258 * 256 * 2;  // 33,816,576 B
  const size_t X1B = (size_t)2048 * 264 * 2;       //  1,081,344 B
  if (ws_size < WPB + X1B) {
    fb_k<<<2048, 256, 0, stream>>>(x, W, b, y);
    return;
  }
  _Float16* Wp  = (_Float16*)d_ws;
  _Float16* X1g = (_Float16*)((char*)d_ws + WPB);

  conv_w_k<<<8256, 256, 0, stream>>>(W, Wp);
  conv_x1_k<<<264, 256, 0, stream>>>(x, X1g);
  init_out_k<<<2048, 256, 0, stream>>>(x, W, b, y);
  gemm_k<<<2048, 256, 0, stream>>>(Wp, X1g, y);
}

// Round 6
// 169.760 us; speedup vs baseline: 2.1914x; 2.1914x over previous
//
#include <hip/hip_runtime.h>
#include <cstdint>
#include <cstddef>

// ---------------------------------------------------------------------------
// y[b,o] = sum_{i,j<257} x1[b,i] x1[b,j] W[o, i*257+j] + bias[o],  x1=[1,x]
//   main : slices ii in [0,258) (257 real + pseudo 257=j-col 256), j in [0,256)
//   corner (256,256) + bias -> init_out kernel (exact fp32)
// Round 6: W re-laid in MFMA FRAGMENT ORDER:
//   Wp2[((ii*8+jc)*16+f)*64 + l][e]  holds  W[o = f*16+(l&15),
//        j = jc*32 + (l>>4)*8 + e]  of slice ii (pseudo 257 = col-256 column).
//   -> every gemm W load is base + l*16: coalesced (4 lines/wave), vs the
//      previous 64-lines-per-load scattered pattern (root cause of r1-r5).
// Register-only core (round-5 verified math): zero LDS, zero barriers.
// BM=32, 4-wave blocks, KSPLIT=16, grid 1024 = 4 blocks/CU; co-resident
// blocks (bid+-256) share split+XCD -> W stream L1-deduped, L2-resident.
// ---------------------------------------------------------------------------

typedef _Float16 half8 __attribute__((ext_vector_type(8)));
typedef float    f32x4 __attribute__((ext_vector_type(4)));

#define LD8(p) (*(const half8*)(p))

// ---- stage 1: W [256][66049] f32 -> Wp2 fragment-ordered f16 ---------------
__global__ void conv_w_k(const float* __restrict__ W, _Float16* __restrict__ Wp) {
  int t  = blockIdx.x * 256 + threadIdx.x;  // 258*8*16*64 = 2,113,536
  int l  = t & 63;
  int f  = (t >> 6) & 15;
  int jc = (t >> 10) & 7;
  int ii = t >> 13;                          // 0..257
  int o  = f * 16 + (l & 15);
  int j0 = jc * 32 + (l >> 4) * 8;
  half8 h;
  if (ii < 257) {
    const float* src = W + (size_t)o * 66049 + (size_t)ii * 257 + j0;
#pragma unroll
    for (int e = 0; e < 8; ++e) h[e] = (_Float16)src[e];
  } else {
    const float* src = W + (size_t)o * 66049 + 256;
#pragma unroll
    for (int e = 0; e < 8; ++e) h[e] = (_Float16)src[(size_t)(j0 + e) * 257];
  }
  *(half8*)(Wp + (size_t)t * 8) = h;
}

// ---- stage 1b: x [2048][256] f32 -> X1g [2048][264] f16 (x1 padded) ---------
__global__ void conv_x1_k(const float* __restrict__ x, _Float16* __restrict__ X1g) {
  int t  = blockIdx.x * 256 + threadIdx.x;    // total 2048*33 = 67584
  int j8 = t % 33;
  int b  = t / 33;
  half8 h;
#pragma unroll
  for (int u = 0; u < 8; ++u) {
    int jj = j8 * 8 + u;
    float v = (jj == 0) ? 1.0f : (jj <= 256 ? x[(size_t)b * 256 + (jj - 1)] : 0.0f);
    h[u] = (_Float16)v;
  }
  *(half8*)(X1g + (size_t)b * 264 + j8 * 8) = h;
}

// ---- init: Y = bias + x1[256]^2 * W[o,66048]  (exact fp32 terms) ------------
__global__ void init_out_k(const float* __restrict__ x, const float* __restrict__ W,
                           const float* __restrict__ bias, float* __restrict__ Y) {
  int o = threadIdx.x;
  int b = blockIdx.x;
  float xl = x[(size_t)b * 256 + 255];
  float w  = W[(size_t)o * 66049 + 66048];
  Y[(size_t)b * 256 + o] = bias[o] + xl * xl * w;
}

// ---- main-loop core: 4 jc-pairs x 2*NII steps, fully static slots -----------
// W stream offsets (halves): step (k, jc) frag nf at
//   wq + (k*8 + jc)*8192 + nf*512   (wq already includes ii0, wave, lane)
template<int NII>
__device__ __forceinline__ void core_fn(
    const _Float16* __restrict__ wq,
    const _Float16* __restrict__ x0,  const _Float16* __restrict__ x1r,
    half8 s80, half8 s81, half8 s82, half8 s83, _Float16 s90, _Float16 s91,
    f32x4 acc[2][4])
{
  half8 sA0, sA1, sA2, sA3, sB0, sB1, sB2, sB3;
  half8 bA0, bA1, bB0, bB1;

  // prologue: base for jc=0/1, W slots for steps (k=0,jc=0) and (k=1,jc=0)
  bA0 = LD8(x0);       bA1 = LD8(x1r);
  bB0 = LD8(x0 + 32);  bB1 = LD8(x1r + 32);
  sA0 = LD8(wq +     0); sA1 = LD8(wq +   512); sA2 = LD8(wq +  1024); sA3 = LD8(wq +  1536);
  sB0 = LD8(wq + 65536); sB1 = LD8(wq + 66048); sB2 = LD8(wq + 66560); sB3 = LD8(wq + 67072);

  for (int jp = 0; jp < 4; ++jp) {
    const int jc0 = 2 * jp;
    const int jcn = (jp < 3) ? jc0 + 2 : 0;     // next-pair jc (jp=3: dummy)
    const _Float16* qb = wq + jc0 * 8192;       // this pair's base
    const _Float16* rb = wq + jcn * 8192;       // next pair's base
    const _Float16* xa0 = x0  + jcn * 32;       // baseA refill (next pair, 1st)
    const _Float16* xa1 = x1r + jcn * 32;
    const _Float16* xb0 = x0  + jcn * 32 + 32;  // baseB refill (next pair, 2nd)
    const _Float16* xb1 = x1r + jcn * 32 + 32;

#pragma unroll
    for (int q = 0; q < 2 * NII; ++q) {
      const int k = (q < NII) ? q : q - NII;    // slice offset (compile-time)
      _Float16 e0 = (k < 8) ? s80[k] : ((k < 16) ? s82[k - 8] : s90);
      _Float16 e1 = (k < 8) ? s81[k] : ((k < 16) ? s83[k - 8] : s91);
      half8 v0 = {e0, e0, e0, e0, e0, e0, e0, e0};
      half8 v1 = {e1, e1, e1, e1, e1, e1, e1, e1};
      half8 af0 = ((q < NII) ? bA0 : bB0) * v0;   // v_pk_mul_f16
      half8 af1 = ((q < NII) ? bA1 : bB1) * v1;

      __builtin_amdgcn_s_setprio(1);
      if ((q & 1) == 0) {
        acc[0][0] = __builtin_amdgcn_mfma_f32_16x16x32_f16(af0, sA0, acc[0][0], 0, 0, 0);
        acc[0][1] = __builtin_amdgcn_mfma_f32_16x16x32_f16(af0, sA1, acc[0][1], 0, 0, 0);
        acc[0][2] = __builtin_amdgcn_mfma_f32_16x16x32_f16(af0, sA2, acc[0][2], 0, 0, 0);
        acc[0][3] = __builtin_amdgcn_mfma_f32_16x16x32_f16(af0, sA3, acc[0][3], 0, 0, 0);
        acc[1][0] = __builtin_amdgcn_mfma_f32_16x16x32_f16(af1, sA0, acc[1][0], 0, 0, 0);
        acc[1][1] = __builtin_amdgcn_mfma_f32_16x16x32_f16(af1, sA1, acc[1][1], 0, 0, 0);
        acc[1][2] = __builtin_amdgcn_mfma_f32_16x16x32_f16(af1, sA2, acc[1][2], 0, 0, 0);
        acc[1][3] = __builtin_amdgcn_mfma_f32_16x16x32_f16(af1, sA3, acc[1][3], 0, 0, 0);
      } else {
        acc[0][0] = __builtin_amdgcn_mfma_f32_16x16x32_f16(af0, sB0, acc[0][0], 0, 0, 0);
        acc[0][1] = __builtin_amdgcn_mfma_f32_16x16x32_f16(af0, sB1, acc[0][1], 0, 0, 0);
        acc[0][2] = __builtin_amdgcn_mfma_f32_16x16x32_f16(af0, sB2, acc[0][2], 0, 0, 0);
        acc[0][3] = __builtin_amdgcn_mfma_f32_16x16x32_f16(af0, sB3, acc[0][3], 0, 0, 0);
        acc[1][0] = __builtin_amdgcn_mfma_f32_16x16x32_f16(af1, sB0, acc[1][0], 0, 0, 0);
        acc[1][1] = __builtin_amdgcn_mfma_f32_16x16x32_f16(af1, sB1, acc[1][1], 0, 0, 0);
        acc[1][2] = __builtin_amdgcn_mfma_f32_16x16x32_f16(af1, sB2, acc[1][2], 0, 0, 0);
        acc[1][3] = __builtin_amdgcn_mfma_f32_16x16x32_f16(af1, sB3, acc[1][3], 0, 0, 0);
      }
      __builtin_amdgcn_s_setprio(0);

      // prefetch step q+2 into the slot just consumed (double buffer)
      const int qq = q + 2;
      if (qq < 2 * NII) {
        const long koff = (long)((qq < NII) ? qq : qq - NII) * 65536
                        + ((qq < NII) ? 0 : 8192);
        if ((q & 1) == 0) {
          sA0 = LD8(qb + koff);        sA1 = LD8(qb + koff + 512);
          sA2 = LD8(qb + koff + 1024); sA3 = LD8(qb + koff + 1536);
        } else {
          sB0 = LD8(qb + koff);        sB1 = LD8(qb + koff + 512);
          sB2 = LD8(qb + koff + 1024); sB3 = LD8(qb + koff + 1536);
        }
      } else {
        const long koff = (long)(qq - 2 * NII) * 65536;   // steps 0/1, next pair
        if ((q & 1) == 0) {
          sA0 = LD8(rb + koff);        sA1 = LD8(rb + koff + 512);
          sA2 = LD8(rb + koff + 1024); sA3 = LD8(rb + koff + 1536);
        } else {
          sB0 = LD8(rb + koff);        sB1 = LD8(rb + koff + 512);
          sB2 = LD8(rb + koff + 1024); sB3 = LD8(rb + koff + 1536);
        }
      }
      if (q == NII)         { bA0 = LD8(xa0); bA1 = LD8(xa1); }
      if (q == 2 * NII - 1) { bB0 = LD8(xb0); bB1 = LD8(xb1); }
    }
  }
}

// ---- main GEMM: virtual A = x1[b,ii] * x1[b,j], B = Wp2 streamed to VGPR ----
__global__ __launch_bounds__(256, 4)
void gemm_k(const _Float16* __restrict__ Wp, const _Float16* __restrict__ X1g,
            float* __restrict__ Y) {
  const int bid = blockIdx.x;
  const int s   = bid & 15;             // split; co-resident bids+-256 share it
  const int mt  = bid >> 4;             // m-tile (BM=32), 0..63
  const int ii0 = s * 16 + (s < 2 ? s : 2);   // splits 0,1: NII=17; else 16

  const int tid = threadIdx.x;
  const int l   = tid & 63;
  const int w   = tid >> 6;   // wave = n-group (64 outputs)
  const int ln  = l & 15;
  const int ks  = l >> 4;

  const int row0 = mt * 32 + ln;
  const int row1 = row0 + 16;
  const _Float16* x0  = X1g + (size_t)row0 * 264 + ks * 8;
  const _Float16* x1r = X1g + (size_t)row1 * 264 + ks * 8;

  // per-slice scalars: x1[row, min(ii0+k, 256)] (pseudo-slice 257 -> x1[256])
  half8 s80, s81, s82, s83;
#pragma unroll
  for (int k = 0; k < 8; ++k) {
    int i1 = ii0 + k;     if (i1 > 256) i1 = 256;
    int i2 = ii0 + 8 + k; if (i2 > 256) i2 = 256;
    s80[k] = X1g[(size_t)row0 * 264 + i1];
    s81[k] = X1g[(size_t)row1 * 264 + i1];
    s82[k] = X1g[(size_t)row0 * 264 + i2];
    s83[k] = X1g[(size_t)row1 * 264 + i2];
  }
  _Float16 s90 = (_Float16)0.f, s91 = (_Float16)0.f;
  if (s < 2) {
    int i3 = ii0 + 16; if (i3 > 256) i3 = 256;
    s90 = X1g[(size_t)row0 * 264 + i3];
    s91 = X1g[(size_t)row1 * 264 + i3];
  }

  // W stream base (halves): frag block (ii0*8 + jc=0)*16 + wave's 4 frags
  const _Float16* wq = Wp + ((size_t)ii0 * 128 + w * 4) * 512 + l * 8;

  f32x4 acc[2][4];
#pragma unroll
  for (int mf = 0; mf < 2; ++mf)
#pragma unroll
    for (int nf = 0; nf < 4; ++nf) acc[mf][nf] = (f32x4){0.f, 0.f, 0.f, 0.f};

  if (s < 2) core_fn<17>(wq, x0, x1r, s80, s81, s82, s83, s90, s91, acc);
  else       core_fn<16>(wq, x0, x1r, s80, s81, s82, s83, s90, s91, acc);

  // ---- epilogue: atomic accumulate (C/D: col=l&15, row=ks*4+r) ----
  float* yb = Y + (size_t)(mt * 32) * 256 + w * 64;
  const int r0 = ks * 4;
#pragma unroll
  for (int mf = 0; mf < 2; ++mf)
#pragma unroll
    for (int nf = 0; nf < 4; ++nf)
#pragma unroll
      for (int r = 0; r < 4; ++r)
        unsafeAtomicAdd(&yb[(size_t)(mf * 16 + r0 + r) * 256 + nf * 16 + ln],
                        acc[mf][nf][r]);
}

// ---- emergency fallback if ws too small (correct, slow) ---------------------
__global__ void fb_k(const float* __restrict__ x, const float* __restrict__ W,
                     const float* __restrict__ bias, float* __restrict__ Y) {
  __shared__ float x1[257];
  int b = blockIdx.x, o = threadIdx.x;
  x1[o + 1] = x[(size_t)b * 256 + o];
  if (o == 0) x1[0] = 1.0f;
  __syncthreads();
  const float* Wr = W + (size_t)o * 66049;
  float acc = bias[o];
  for (int i = 0; i < 257; ++i) {
    const float* wr = Wr + (size_t)i * 257;
    float p = 0.f;
    for (int j = 0; j < 257; ++j) p = fmaf(x1[j], wr[j], p);
    acc = fmaf(x1[i], p, acc);
  }
  Y[(size_t)b * 256 + o] = acc;
}

extern "C" void kernel_launch(void* const* d_in, const int* in_sizes, int n_in,
                              void* d_out, int out_size, void* d_ws, size_t ws_size,
                              hipStream_t stream) {
  const float* x = (const float*)d_in[0];
  const float* W = (const float*)d_in[1];
  const float* b = (const float*)d_in[2];
  float* y = (float*)d_out;

  const size_t WPB = (size_t)258 * 8 * 16 * 64 * 16;  // 33,816,576 B
  const size_t X1B = (size_t)2048 * 264 * 2;          //  1,081,344 B
  if (ws_size < WPB + X1B) {
    fb_k<<<2048, 256, 0, stream>>>(x, W, b, y);
    return;
  }
  _Float16* Wp  = (_Float16*)d_ws;
  _Float16* X1g = (_Float16*)((char*)d_ws + WPB);

  conv_w_k<<<8256, 256, 0, stream>>>(W, Wp);
  conv_x1_k<<<264, 256, 0, stream>>>(x, X1g);
  init_out_k<<<2048, 256, 0, stream>>>(x, W, b, y);
  gemm_k<<<1024, 256, 0, stream>>>(Wp, X1g, y);
}

// Round 7
// 145.935 us; speedup vs baseline: 2.5491x; 1.1633x over previous
//
#include <hip/hip_runtime.h>
#include <cstdint>
#include <cstddef>

// ---------------------------------------------------------------------------
// y[b,o] = sum_{i,j<257} x1[b,i] x1[b,j] W[o, i*257+j] + bias[o],  x1=[1,x]
//   main : slices ii in [0,258) (257 real + pseudo 257=j-col 256), j in [0,256)
//   corner (256,256) + bias -> init_out kernel (exact fp32)
// Round 7: m97-style staging discipline on fragment-ordered Wp.
//   W is DMA'd global->LDS (global_load_lds x2/thread/step, lane-linear into
//   the 16KB fragment block), 4 LDS buffers, prefetch depth 3, counted
//   vmcnt(4) (never 0 in steady state), ONE raw s_barrier per step,
//   setprio(1) around the 16-MFMA cluster. The DMA dependence is invisible
//   to the compiler, so it cannot collapse this pipeline (root cause of
//   rounds 3-6: compiler serialized register double-buffers).
// A-operand virtual: cur[4] x1 frags (16 VGPR, 4 global loads per jc) times
// per-slice scalar from a 2.3KB LDS table. acc 64 VGPR. ~105 live regs.
// Block 512thr = 8 waves (2m x 4n), BM=128, BN=256, wave tile 64x64.
// KSPLIT=32, grid 512 = 2 blocks/CU (16 waves/CU); split->XCD pinned (s%8).
// ---------------------------------------------------------------------------

typedef _Float16 half8 __attribute__((ext_vector_type(8)));
typedef float    f32x4 __attribute__((ext_vector_type(4)));

#define LD8(p) (*(const half8*)(p))
#define WAITVM(N) asm volatile("s_waitcnt vmcnt(" #N ")" ::: "memory")
#define WAITLGKM  asm volatile("s_waitcnt lgkmcnt(0)" ::: "memory")

__device__ __forceinline__ void gload_lds16(const void* g, void* lds) {
  __builtin_amdgcn_global_load_lds(
      (const __attribute__((address_space(1))) uint32_t*)g,
      (__attribute__((address_space(3))) uint32_t*)lds, 16, 0, 0);
}

// ---- stage 1: W [256][66049] f32 -> Wp fragment-ordered f16 ----------------
// Wp[((ii*8+jc)*16+f)*64 + l][e] = W[o=f*16+(l&15), j=jc*32+(l>>4)*8+e] slice ii
__global__ void conv_w_k(const float* __restrict__ W, _Float16* __restrict__ Wp) {
  int t  = blockIdx.x * 256 + threadIdx.x;  // 258*8*16*64 = 2,113,536
  int l  = t & 63;
  int f  = (t >> 6) & 15;
  int jc = (t >> 10) & 7;
  int ii = t >> 13;                          // 0..257
  int o  = f * 16 + (l & 15);
  int j0 = jc * 32 + (l >> 4) * 8;
  half8 h;
  if (ii < 257) {
    const float* src = W + (size_t)o * 66049 + (size_t)ii * 257 + j0;
#pragma unroll
    for (int e = 0; e < 8; ++e) h[e] = (_Float16)src[e];
  } else {
    const float* src = W + (size_t)o * 66049 + 256;
#pragma unroll
    for (int e = 0; e < 8; ++e) h[e] = (_Float16)src[(size_t)(j0 + e) * 257];
  }
  *(half8*)(Wp + (size_t)t * 8) = h;
}

// ---- stage 1b: x [2048][256] f32 -> X1g [2048][264] f16 (x1 padded) ---------
__global__ void conv_x1_k(const float* __restrict__ x, _Float16* __restrict__ X1g) {
  int t  = blockIdx.x * 256 + threadIdx.x;    // total 2048*33 = 67584
  int j8 = t % 33;
  int b  = t / 33;
  half8 h;
#pragma unroll
  for (int u = 0; u < 8; ++u) {
    int jj = j8 * 8 + u;
    float v = (jj == 0) ? 1.0f : (jj <= 256 ? x[(size_t)b * 256 + (jj - 1)] : 0.0f);
    h[u] = (_Float16)v;
  }
  *(half8*)(X1g + (size_t)b * 264 + j8 * 8) = h;
}

// ---- init: Y = bias + x1[256]^2 * W[o,66048]  (exact fp32 terms) ------------
__global__ void init_out_k(const float* __restrict__ x, const float* __restrict__ W,
                           const float* __restrict__ bias, float* __restrict__ Y) {
  int o = threadIdx.x;
  int b = blockIdx.x;
  float xl = x[(size_t)b * 256 + 255];
  float w  = W[(size_t)o * 66049 + 66048];
  Y[(size_t)b * 256 + o] = bias[o] + xl * xl * w;
}

// ---- main GEMM --------------------------------------------------------------
__global__ __launch_bounds__(512, 4)
void gemm_k(const _Float16* __restrict__ Wp, const _Float16* __restrict__ X1g,
            float* __restrict__ Y) {
  __shared__ __align__(16) _Float16 wbuf[4 * 8192];   // 4 x 16 KB step buffers
  __shared__ _Float16 scal[9 * 128];                  // x1[m, ii0+k], k<nii

  const int bid = blockIdx.x;
  const int s   = bid & 31;              // split; XCD = s%8 (4 slices/XCD L2)
  const int mt  = bid >> 5;              // m-tile (BM=128), 0..15
  const int nii = (s < 2) ? 9 : 8;       // 258 = 2*9 + 30*8
  const int ii0 = s * 8 + (s < 2 ? s : 2);

  const int tid = threadIdx.x;
  const int l   = tid & 63;
  const int w   = tid >> 6;   // wave 0..7
  const int wm  = w >> 2;     // m-group 0..1
  const int wn  = w & 3;      // n-group 0..3
  const int ln  = l & 15;
  const int ks  = l >> 4;

  // ---- scal table: scal[k][m] = x1[mt*128+m, min(ii0+k,256)] ----
  for (int t = tid; t < nii * 128; t += 512) {
    int k = t >> 7, m = t & 127;
    int ii = ii0 + k; if (ii > 256) ii = 256;
    scal[k * 128 + m] = X1g[(size_t)(mt * 128 + m) * 264 + ii];
  }

  // x1 row pointer for this lane's A-fragment rows (rows wm*64 + mf*16 + ln)
  const _Float16* xr = X1g + (size_t)(mt * 128 + wm * 64 + ln) * 264 + ks * 8;

  // W staging: per-thread global src (lane-linear), wave-uniform LDS dest
  const char* gW   = (const char*)Wp + (size_t)ii0 * 131072 + w * 1024 + l * 16;
  char*       ldsW = (char*)wbuf + w * 1024;

  const int nsteps = nii * 8;

  // stage step st' at cursor (sjc, sk): block offset (sk*8 + sjc)*16384 B
  // prologue: stage steps 0,1,2  (jc=0, k=0..2)
  gload_lds16(gW +     0, ldsW);            gload_lds16(gW +  8192, ldsW + 8192);
  gload_lds16(gW + 131072, ldsW + 16384);   gload_lds16(gW + 139264, ldsW + 24576);
  gload_lds16(gW + 262144, ldsW + 32768);   gload_lds16(gW + 270336, ldsW + 40960);
  WAITVM(4);        // stage(0) complete (st1, st2 may remain)
  WAITLGKM;         // scal table writes visible
  __builtin_amdgcn_s_barrier();

  f32x4 acc[4][4];
#pragma unroll
  for (int mf = 0; mf < 4; ++mf)
#pragma unroll
    for (int nf = 0; nf < 4; ++nf) acc[mf][nf] = (f32x4){0.f, 0.f, 0.f, 0.f};

  int st  = 0;
  int sk  = 3, sjc = 0;    // stage cursor positioned at step 3
  for (int jc = 0; jc < 8; ++jc) {
    // A base fragments for this j-chunk: x1[row, jc*32 + ks*8 ..+7]
    half8 cur[4];
#pragma unroll
    for (int mf = 0; mf < 4; ++mf)
      cur[mf] = LD8(xr + (size_t)(mf * 16) * 264 + jc * 32);

    for (int k = 0; k < nii; ++k, ++st) {
      // prefetch step st+3 (2 x global_load_lds into buffer (st+3)&3)
      if (st + 3 < nsteps) {
        const int blk = (sk * 8 + sjc) * 16384;
        char* d = ldsW + ((st + 3) & 3) * 16384;
        gload_lds16(gW + blk, d);
        gload_lds16(gW + blk + 8192, d + 8192);
        ++sk; if (sk == nii) { sk = 0; ++sjc; }
      }

      // per-slice scalars (broadcast within 16-lane groups; no conflicts)
      _Float16 sv0 = scal[k * 128 + wm * 64 +  0 + ln];
      _Float16 sv1 = scal[k * 128 + wm * 64 + 16 + ln];
      _Float16 sv2 = scal[k * 128 + wm * 64 + 32 + ln];
      _Float16 sv3 = scal[k * 128 + wm * 64 + 48 + ln];

      // W fragments for this wave's n-group (conflict-free ds_read_b128)
      const _Float16* wb = wbuf + (st & 3) * 8192 + (wn * 4) * 512 + l * 8;
      half8 bf0 = LD8(wb);
      half8 bf1 = LD8(wb + 512);
      half8 bf2 = LD8(wb + 1024);
      half8 bf3 = LD8(wb + 1536);

      __builtin_amdgcn_s_setprio(1);
      {
        half8 v0 = {sv0, sv0, sv0, sv0, sv0, sv0, sv0, sv0};
        half8 af = cur[0] * v0;
        acc[0][0] = __builtin_amdgcn_mfma_f32_16x16x32_f16(af, bf0, acc[0][0], 0, 0, 0);
        acc[0][1] = __builtin_amdgcn_mfma_f32_16x16x32_f16(af, bf1, acc[0][1], 0, 0, 0);
        acc[0][2] = __builtin_amdgcn_mfma_f32_16x16x32_f16(af, bf2, acc[0][2], 0, 0, 0);
        acc[0][3] = __builtin_amdgcn_mfma_f32_16x16x32_f16(af, bf3, acc[0][3], 0, 0, 0);
      }
      {
        half8 v1 = {sv1, sv1, sv1, sv1, sv1, sv1, sv1, sv1};
        half8 af = cur[1] * v1;
        acc[1][0] = __builtin_amdgcn_mfma_f32_16x16x32_f16(af, bf0, acc[1][0], 0, 0, 0);
        acc[1][1] = __builtin_amdgcn_mfma_f32_16x16x32_f16(af, bf1, acc[1][1], 0, 0, 0);
        acc[1][2] = __builtin_amdgcn_mfma_f32_16x16x32_f16(af, bf2, acc[1][2], 0, 0, 0);
        acc[1][3] = __builtin_amdgcn_mfma_f32_16x16x32_f16(af, bf3, acc[1][3], 0, 0, 0);
      }
      {
        half8 v2 = {sv2, sv2, sv2, sv2, sv2, sv2, sv2, sv2};
        half8 af = cur[2] * v2;
        acc[2][0] = __builtin_amdgcn_mfma_f32_16x16x32_f16(af, bf0, acc[2][0], 0, 0, 0);
        acc[2][1] = __builtin_amdgcn_mfma_f32_16x16x32_f16(af, bf1, acc[2][1], 0, 0, 0);
        acc[2][2] = __builtin_amdgcn_mfma_f32_16x16x32_f16(af, bf2, acc[2][2], 0, 0, 0);
        acc[2][3] = __builtin_amdgcn_mfma_f32_16x16x32_f16(af, bf3, acc[2][3], 0, 0, 0);
      }
      {
        half8 v3 = {sv3, sv3, sv3, sv3, sv3, sv3, sv3, sv3};
        half8 af = cur[3] * v3;
        acc[3][0] = __builtin_amdgcn_mfma_f32_16x16x32_f16(af, bf0, acc[3][0], 0, 0, 0);
        acc[3][1] = __builtin_amdgcn_mfma_f32_16x16x32_f16(af, bf1, acc[3][1], 0, 0, 0);
        acc[3][2] = __builtin_amdgcn_mfma_f32_16x16x32_f16(af, bf2, acc[3][2], 0, 0, 0);
        acc[3][3] = __builtin_amdgcn_mfma_f32_16x16x32_f16(af, bf3, acc[3][3], 0, 0, 0);
      }
      __builtin_amdgcn_s_setprio(0);

      // counted drain: stage(st+1) must be complete before next step
      if (st < nsteps - 1) {
        if (st <= nsteps - 4)      { WAITVM(4); }
        else if (st == nsteps - 3) { WAITVM(2); }
        else                       { WAITVM(0); }
        __builtin_amdgcn_s_barrier();
      }
    }
  }

  // ---- epilogue: atomic accumulate (C/D: col=l&15, row=ks*4+r) ----
  float* yb = Y + (size_t)(mt * 128 + wm * 64) * 256 + wn * 64;
  const int r0 = ks * 4;
#pragma unroll
  for (int mf = 0; mf < 4; ++mf)
#pragma unroll
    for (int nf = 0; nf < 4; ++nf)
#pragma unroll
      for (int r = 0; r < 4; ++r)
        unsafeAtomicAdd(&yb[(size_t)(mf * 16 + r0 + r) * 256 + nf * 16 + ln],
                        acc[mf][nf][r]);
}

// ---- emergency fallback if ws too small (correct, slow) ---------------------
__global__ void fb_k(const float* __restrict__ x, const float* __restrict__ W,
                     const float* __restrict__ bias, float* __restrict__ Y) {
  __shared__ float x1[257];
  int b = blockIdx.x, o = threadIdx.x;
  x1[o + 1] = x[(size_t)b * 256 + o];
  if (o == 0) x1[0] = 1.0f;
  __syncthreads();
  const float* Wr = W + (size_t)o * 66049;
  float acc = bias[o];
  for (int i = 0; i < 257; ++i) {
    const float* wr = Wr + (size_t)i * 257;
    float p = 0.f;
    for (int j = 0; j < 257; ++j) p = fmaf(x1[j], wr[j], p);
    acc = fmaf(x1[i], p, acc);
  }
  Y[(size_t)b * 256 + o] = acc;
}

extern "C" void kernel_launch(void* const* d_in, const int* in_sizes, int n_in,
                              void* d_out, int out_size, void* d_ws, size_t ws_size,
                              hipStream_t stream) {
  const float* x = (const float*)d_in[0];
  const float* W = (const float*)d_in[1];
  const float* b = (const float*)d_in[2];
  float* y = (float*)d_out;

  const size_t WPB = (size_t)258 * 8 * 16 * 64 * 16;  // 33,816,576 B
  const size_t X1B = (size_t)2048 * 264 * 2;          //  1,081,344 B
  if (ws_size < WPB + X1B) {
    fb_k<<<2048, 256, 0, stream>>>(x, W, b, y);
    return;
  }
  _Float16* Wp  = (_Float16*)d_ws;
  _Float16* X1g = (_Float16*)((char*)d_ws + WPB);

  conv_w_k<<<8256, 256, 0, stream>>>(W, Wp);
  conv_x1_k<<<264, 256, 0, stream>>>(x, X1g);
  init_out_k<<<2048, 256, 0, stream>>>(x, W, b, y);
  gemm_k<<<512, 512, 0, stream>>>(Wp, X1g, y);
}